// Round 16
// baseline (123.546 us; speedup 1.0000x reference)
//
#include <hip/hip_runtime.h>
#include <math.h>

#define Cn 192
#define Bn 8
#define Tn 4096
#define HW 64

typedef unsigned short u16;
typedef unsigned int u32;
typedef __attribute__((ext_vector_type(8))) __bf16 bf16x8;
typedef __attribute__((ext_vector_type(16))) float f32x16;

__device__ __forceinline__ void gload16(const void* g, void* l) {
    __builtin_amdgcn_global_load_lds(
        (const __attribute__((address_space(1))) void*)g,
        (__attribute__((address_space(3))) void*)l, 16, 0, 0);
}

__device__ __forceinline__ void split_bf16(float x, u16 &h, u16 &l) {
    u32 u = __float_as_uint(x);
    u32 uh = (u + 0x7FFFu + ((u >> 16) & 1u)) & 0xFFFF0000u;
    h = (u16)(uh >> 16);
    float r = x - __uint_as_float(uh);
    u32 ur = __float_as_uint(r);
    l = (u16)((ur + 0x7FFFu + ((ur >> 16) & 1u)) >> 16);
}

// ---------------------------------------------------------------------------
// Kernel 1: omni_shift (fused 25-tap depthwise conv) -> split bf16 hi/lo out.
// Blocks >= 1536 perform the weight hi/lo split (fused to save a dispatch).
// ---------------------------------------------------------------------------
__global__ __launch_bounds__(256) void omni_kernel(const float* __restrict__ x,
                                                   const float* __restrict__ alpha,
                                                   const float* __restrict__ dw1,
                                                   const float* __restrict__ dw3,
                                                   const float* __restrict__ dw5,
                                                   const float* __restrict__ Wk,
                                                   const float* __restrict__ Wv,
                                                   const float* __restrict__ Wr,
                                                   const float* __restrict__ Wo,
                                                   u16* __restrict__ xhi,
                                                   u16* __restrict__ xlo,
                                                   u16* __restrict__ wh,
                                                   u16* __restrict__ wl) {
    const int tid = threadIdx.x;
    if (blockIdx.x >= 1536) {
        const int base = (blockIdx.x - 1536) * 768;
        #pragma unroll
        for (int jj = 0; jj < 3; ++jj) {
            int idx = base + jj * 256 + tid;
            int mat = idx / 36864;
            int off = idx - mat * 36864;
            const float* src = (mat == 0) ? Wk : (mat == 1) ? Wv : (mat == 2) ? Wr : Wo;
            u16 h, l;
            split_bf16(src[off], h, l);
            wh[idx] = h;
            wl[idx] = l;
        }
        return;
    }

    const int plane = blockIdx.x;          // b*C + c
    const int c = plane % Cn;
    const float* xin = x + (size_t)plane * Tn;
    u16* oh = xhi + (size_t)plane * Tn;
    u16* ol = xlo + (size_t)plane * Tn;

    __shared__ float tile[68 * 68];
    __shared__ float wk[25];

    if (tid == 0) {
        const float a0 = alpha[0], a1 = alpha[1], a2 = alpha[2], a3 = alpha[3];
        #pragma unroll
        for (int j = 0; j < 25; ++j) wk[j] = a3 * dw5[c * 25 + j];
        #pragma unroll
        for (int dy = 0; dy < 3; ++dy)
            #pragma unroll
            for (int dx = 0; dx < 3; ++dx)
                wk[(dy + 1) * 5 + (dx + 1)] += a2 * dw3[c * 9 + dy * 3 + dx];
        wk[12] += a1 * dw1[c] + a0;
    }
    for (int i = tid; i < 68 * 68; i += 256) {
        int r = i / 68, cc = i - r * 68;
        int gy = r - 2, gx = cc - 2;
        float v = 0.f;
        if (gy >= 0 && gy < HW && gx >= 0 && gx < HW) v = xin[gy * HW + gx];
        tile[i] = v;
    }
    __syncthreads();

    const int py = tid >> 3;          // 0..31
    const int px0 = (tid & 7) << 3;   // 0,8,..,56

    #pragma unroll
    for (int half = 0; half < 2; ++half) {
        const int y = py + half * 32;
        float row[5][12];
        #pragma unroll
        for (int dy = 0; dy < 5; ++dy) {
            const float4* rp = (const float4*)&tile[(y + dy) * 68 + px0];
            float4 r0 = rp[0], r1 = rp[1], r2 = rp[2];
            row[dy][0] = r0.x; row[dy][1] = r0.y; row[dy][2]  = r0.z; row[dy][3]  = r0.w;
            row[dy][4] = r1.x; row[dy][5] = r1.y; row[dy][6]  = r1.z; row[dy][7]  = r1.w;
            row[dy][8] = r2.x; row[dy][9] = r2.y; row[dy][10] = r2.z; row[dy][11] = r2.w;
        }
        u32 ph[4], pl[4];
        #pragma unroll
        for (int jj = 0; jj < 8; ++jj) {
            float acc = 0.f;
            #pragma unroll
            for (int dy = 0; dy < 5; ++dy)
                #pragma unroll
                for (int dx = 0; dx < 5; ++dx)
                    acc = fmaf(row[dy][jj + dx], wk[dy * 5 + dx], acc);
            u16 h, l2;
            split_bf16(acc, h, l2);
            if (jj & 1) { ph[jj >> 1] |= ((u32)h) << 16; pl[jj >> 1] |= ((u32)l2) << 16; }
            else        { ph[jj >> 1] = h;               pl[jj >> 1] = l2; }
        }
        *(uint4*)&oh[y * 64 + px0] = make_uint4(ph[0], ph[1], ph[2], ph[3]);
        *(uint4*)&ol[y * 64 + px0] = make_uint4(pl[0], pl[1], pl[2], pl[3]);
    }
}

// ---------------------------------------------------------------------------
// Kernel 2: fused k/v/sr projection GEMM (R10/R15-measured best: t-tile 128,
// 43 KB pool, NO in-kernel summary, terminates with stores in flight).
// ---------------------------------------------------------------------------
__global__ __launch_bounds__(256) void gemm_proj(const u16* __restrict__ wh,
                                                 const u16* __restrict__ wl,
                                                 const u16* __restrict__ Xh,
                                                 const u16* __restrict__ Xl,
                                                 float* __restrict__ O0,
                                                 float* __restrict__ O1,
                                                 float* __restrict__ O2) {
    __shared__ u16 Ah_[3 * 64 * 32], Al_[3 * 64 * 32];
    __shared__ u16 Bh_[128 * 36], Bl_[128 * 36];

    const int tid  = threadIdx.x;
    const int l    = tid & 63;
    const int wave = tid >> 6;
    const int wm   = wave >> 1, wn = wave & 1;
    const int m0   = blockIdx.y * 64;
    const int t0   = blockIdx.x * 128;
    const size_t xb = (size_t)blockIdx.z * Cn * Tn;
    const int cpair = tid & 15;         // c-pair 0..15
    const int toct  = tid >> 4;         // t-oct 0..15

    f32x16 acc[3][2];
    #pragma unroll
    for (int m = 0; m < 3; ++m)
        #pragma unroll
        for (int nf = 0; nf < 2; ++nf)
            #pragma unroll
            for (int r = 0; r < 16; ++r) acc[m][nf][r] = 0.f;

    uint4 rh0, rh1, rl0, rl1;           // B reg-stage (one K-step)

    auto loadB = [&](int k0) {
        size_t g = xb + (size_t)(k0 + 2 * cpair) * Tn + t0 + toct * 8;
        rh0 = *(const uint4*)&Xh[g];
        rh1 = *(const uint4*)&Xh[g + Tn];
        rl0 = *(const uint4*)&Xl[g];
        rl1 = *(const uint4*)&Xl[g + Tn];
    };
    auto writeB = [&]() {
        const u32 h0[4] = {rh0.x, rh0.y, rh0.z, rh0.w};
        const u32 h1[4] = {rh1.x, rh1.y, rh1.z, rh1.w};
        const u32 l0[4] = {rl0.x, rl0.y, rl0.z, rl0.w};
        const u32 l1[4] = {rl1.x, rl1.y, rl1.z, rl1.w};
        #pragma unroll
        for (int j = 0; j < 8; ++j) {
            int t = toct * 8 + j;
            int sh = 16 * (j & 1);
            u32 a = (h0[j >> 1] >> sh) & 0xFFFFu;
            u32 b = (h1[j >> 1] >> sh) & 0xFFFFu;
            *(u32*)&Bh_[t * 36 + 2 * cpair] = a | (b << 16);
            u32 c = (l0[j >> 1] >> sh) & 0xFFFFu;
            u32 d = (l1[j >> 1] >> sh) & 0xFFFFu;
            *(u32*)&Bl_[t * 36 + 2 * cpair] = c | (d << 16);
        }
    };
    auto stageA = [&](int k0) {
        #pragma unroll
        for (int i = 0; i < 3; ++i) {
            int idx = i * 256 + tid;
            int row = idx >> 2;
            int cb  = (idx & 3) ^ ((row >> 1) & 3);
            int grow = (row >> 6) * 192 + m0 + (row & 63);
            gload16(wh + (size_t)grow * Cn + k0 + cb * 8, Ah_ + idx * 8);
            gload16(wl + (size_t)grow * Cn + k0 + cb * 8, Al_ + idx * 8);
        }
    };
    auto compute = [&]() {
        #pragma unroll
        for (int kh = 0; kh < 2; ++kh) {
            const int cbb = kh * 2 + (l >> 5);
            bf16x8 ah[3], al[3];
            #pragma unroll
            for (int m = 0; m < 3; ++m) {
                int r = m * 64 + wm * 32 + (l & 31);
                int off = r * 32 + ((cbb ^ ((r >> 1) & 3)) << 3);
                ah[m] = *(const bf16x8*)&Ah_[off];
                al[m] = *(const bf16x8*)&Al_[off];
            }
            #pragma unroll
            for (int nf = 0; nf < 2; ++nf) {
                int t = wn * 64 + nf * 32 + (l & 31);
                int o = t * 36 + cbb * 8;
                union { uint2 q[2]; bf16x8 v; } th, tl2;
                th.q[0]  = *(const uint2*)&Bh_[o];
                th.q[1]  = *(const uint2*)&Bh_[o + 4];
                tl2.q[0] = *(const uint2*)&Bl_[o];
                tl2.q[1] = *(const uint2*)&Bl_[o + 4];
                #pragma unroll
                for (int m = 0; m < 3; ++m) {
                    acc[m][nf] = __builtin_amdgcn_mfma_f32_32x32x16_bf16(ah[m], th.v,  acc[m][nf], 0, 0, 0);
                    acc[m][nf] = __builtin_amdgcn_mfma_f32_32x32x16_bf16(ah[m], tl2.v, acc[m][nf], 0, 0, 0);
                    acc[m][nf] = __builtin_amdgcn_mfma_f32_32x32x16_bf16(al[m], th.v,  acc[m][nf], 0, 0, 0);
                }
            }
        }
    };

    loadB(0);
    stageA(0);
    writeB();                           // waits vmcnt on B regs
    __syncthreads();                    // drains A gloads + B writes visible
    loadB(32);
    for (int ks = 0; ks < 6; ++ks) {
        compute();
        if (ks < 5) {
            __syncthreads();            // readers done with LDS
            writeB();                   // B regs from prefetch
            stageA((ks + 1) * 32);
            __syncthreads();            // A drained + B writes visible
            if (ks < 4) loadB((ks + 2) * 32);
        }
    }

    // ---- epilogue: global stores of k, v, sr (kernel ends with stores in flight)
    float* Os[3] = {O0, O1, O2};
    #pragma unroll
    for (int m = 0; m < 3; ++m) {
        float* O = Os[m] + (size_t)blockIdx.z * Cn * Tn;
        #pragma unroll
        for (int nf = 0; nf < 2; ++nf) {
            int col = t0 + wn * 64 + nf * 32 + (l & 31);
            #pragma unroll
            for (int r = 0; r < 16; ++r) {
                int row = m0 + wm * 32 + (r & 3) + 8 * (r >> 2) + 4 * (l >> 5);
                O[(size_t)row * Tn + col] = acc[m][nf][r];
            }
        }
    }
}

// ---------------------------------------------------------------------------
// Kernel 3: wkv_stats — per-(b,d) row: per-16-chunk summaries from k,v
// (L3-hot re-read) + cross-chunk Hillis-Steele scan -> exclusive states.
// ---------------------------------------------------------------------------
__global__ __launch_bounds__(256) void wkv_stats(const float* __restrict__ kg,
                                                 const float* __restrict__ vg,
                                                 const float* __restrict__ decay,
                                                 float4* __restrict__ states) {
    const int row = blockIdx.x;       // b*C + d
    const int d = row % Cn;
    const float* kr = kg + (size_t)row * Tn;
    const float* vr = vg + (size_t)row * Tn;

    const int tid = threadIdx.x;
    const int t0 = tid * 16;

    float kk[16], vv[16];
    #pragma unroll
    for (int j = 0; j < 16; j += 4) {
        *(float4*)&kk[j] = *(const float4*)&kr[t0 + j];
        *(float4*)&vv[j] = *(const float4*)&vr[t0 + j];
    }

    const float ww = decay[d] * (1.0f / (float)Tn);
    const float lam = expf(-ww);
    const float lam16 = expf(-16.0f * ww);

    float a[16];
    #pragma unroll
    for (int j = 0; j < 16; ++j) a[j] = expf(kk[j]);

    float SN = 0.f, SD = 0.f;
    #pragma unroll
    for (int j = 0; j < 16; ++j) { SN = fmaf(lam, SN, a[j] * vv[j]); SD = fmaf(lam, SD, a[j]); }
    float BN = 0.f, BD = 0.f;
    #pragma unroll
    for (int j = 15; j >= 0; --j) { BN = fmaf(lam, BN, a[j] * vv[j]); BD = fmaf(lam, BD, a[j]); }

    __shared__ float sN[2][256], sD[2][256];

    sN[0][tid] = SN; sD[0][tid] = SD;
    __syncthreads();
    int src = 0;
    float f = lam16;
    for (int o = 1; o < 256; o <<= 1) {
        float nN = sN[src][tid], nD = sD[src][tid];
        if (tid >= o) { nN = fmaf(f, sN[src][tid - o], nN); nD = fmaf(f, sD[src][tid - o], nD); }
        sN[src ^ 1][tid] = nN; sD[src ^ 1][tid] = nD;
        __syncthreads();
        src ^= 1; f = f * f;
    }
    const float CfN = (tid > 0) ? sN[src][tid - 1] : 0.f;
    const float CfD = (tid > 0) ? sD[src][tid - 1] : 0.f;
    __syncthreads();

    sN[0][tid] = BN; sD[0][tid] = BD;
    __syncthreads();
    src = 0; f = lam16;
    for (int o = 1; o < 256; o <<= 1) {
        float nN = sN[src][tid], nD = sD[src][tid];
        if (tid + o < 256) { nN = fmaf(f, sN[src][tid + o], nN); nD = fmaf(f, sD[src][tid + o], nD); }
        sN[src ^ 1][tid] = nN; sD[src ^ 1][tid] = nD;
        __syncthreads();
        src ^= 1; f = f * f;
    }
    const float CbN = (tid < 255) ? sN[src][tid + 1] : 0.f;
    const float CbD = (tid < 255) ? sD[src][tid + 1] : 0.f;

    const int b = row / Cn;
    states[((size_t)(b * 256 + tid)) * Cn + d] = make_float4(CfN, CfD, CbN, CbD);
}

// ---------------------------------------------------------------------------
// Kernel 4: wkv_out — block (b, t-tile 128) x all 192 d, 512 threads.
// NEW: combine phase reads k/v/sr via COALESCED gload_lds staging of
// [192 d][16 t] chunk-tiles (16 lines/wave-instr instead of 64 on the old
// per-row gather), then threads 0..191 scan from LDS. Identical math/order.
// GEMM phase unchanged (dbuf-A, R14/R15-validated). Stage pool aliases the
// GEMM A buffers. LDS ~149.5 KB, 1 block/CU.
// ---------------------------------------------------------------------------
__global__ __launch_bounds__(512) void wkv_out(const float* __restrict__ kb,
                                               const float* __restrict__ vb,
                                               const float* __restrict__ srl,
                                               const float4* __restrict__ states,
                                               const float* __restrict__ decay,
                                               const float* __restrict__ boost,
                                               const u16* __restrict__ wh,
                                               const u16* __restrict__ wl,
                                               float* __restrict__ out) {
    constexpr int ASZ = 192 * 32;      // u16 per A buffer (hi or lo)
    __shared__ u16 Yh_[128 * 196], Yl_[128 * 196];
    __shared__ __align__(16) char pool_[49152];   // GEMM: Ah(2buf)+Al(2buf); combine: kS/vS/sS
    u16* Ah_ = (u16*)pool_;                        // 2*ASZ u16 = 24576 B
    u16* Al_ = (u16*)(pool_ + 24576);              // 24576 B
    float* kS = (float*)pool_;                     // 192*16*4 = 12288 B
    float* vS = (float*)(pool_ + 12288);           // 12288 B
    float* sS = (float*)(pool_ + 24576);           // 12288 B

    const int tid = threadIdx.x;
    const int b = blockIdx.y;
    const int t0 = blockIdx.x * 128;

    // per-thread scan constants (d = tid for math threads)
    const int dm = (tid < Cn) ? tid : 0;
    const float lamM = expf(-decay[dm] * (1.0f / (float)Tn));
    const float uM   = boost[dm] * (1.0f / (float)Tn);

    // coalesced stage of one [192][16] f32 chunk-tile: row d, seg of 4 floats
    auto stage1 = [&](const float* g, float* s) {
        int r = tid;                                     // 0..511
        gload16(g + (size_t)(r >> 2) * Tn + (r & 3) * 4, (char*)s + r * 16);
        if (tid < 256) {
            r = 512 + tid;                               // 512..767
            gload16(g + (size_t)(r >> 2) * Tn + (r & 3) * 4, (char*)s + r * 16);
        }
    };

    const float* kc0 = kb  + (size_t)b * Cn * Tn + t0;
    const float* vc0 = vb  + (size_t)b * Cn * Tn + t0;
    const float* sc0 = srl + (size_t)b * Cn * Tn + t0;

    for (int ch = 0; ch < 8; ++ch) {
        stage1(kc0 + ch * 16, kS);
        stage1(vc0 + ch * 16, vS);
        stage1(sc0 + ch * 16, sS);
        __syncthreads();                 // drains gloads -> tiles ready

        if (tid < Cn) {
            const int d = tid;
            const float4 st = states[((size_t)(b * 256 + (t0 >> 4) + ch)) * Cn + d];
            float kk[16], vv[16], sl[16];
            #pragma unroll
            for (int j = 0; j < 16; j += 4) {
                *(float4*)&kk[j] = *(const float4*)&kS[d * 16 + j];
                *(float4*)&vv[j] = *(const float4*)&vS[d * 16 + j];
                *(float4*)&sl[j] = *(const float4*)&sS[d * 16 + j];
            }
            float a[16];
            #pragma unroll
            for (int j = 0; j < 16; ++j) a[j] = expf(kk[j]);

            float fN[16], fD[16];
            float cN = st.x, cD = st.y;
            #pragma unroll
            for (int j = 0; j < 16; ++j) {
                fN[j] = cN; fD[j] = cD;
                cN = fmaf(lamM, cN, a[j] * vv[j]);
                cD = fmaf(lamM, cD, a[j]);
            }
            float bN = st.z, bD = st.w;
            #pragma unroll
            for (int j = 15; j >= 0; --j) {
                const float es = expf(uM + kk[j]);
                const float y = (fN[j] + bN + es * vv[j]) / (fD[j] + bD + es);
                const float sig = 1.0f / (1.0f + expf(-sl[j]));
                u16 h, l2;
                split_bf16(sig * y, h, l2);
                const int t = ch * 16 + j;
                Yh_[t * 196 + d] = h;
                Yl_[t * 196 + d] = l2;
                bN = fmaf(lamM, bN, a[j] * vv[j]);
                bD = fmaf(lamM, bD, a[j]);
            }
        }
        __syncthreads();                 // math done before next stage overwrite
    }

    // ---- out-projection GEMM: M=192 (w_out rows), N=128 (t), K=192 (d) ----
    const int l = tid & 63;
    const int wave = tid >> 6;
    const int wm = wave >> 2;           // 0..1  (96 M-rows each)
    const int wn = wave & 3;            // 0..3  (32 t-cols each)

    f32x16 acc[3];
    #pragma unroll
    for (int mf = 0; mf < 3; ++mf)
        #pragma unroll
        for (int r = 0; r < 16; ++r) acc[mf][r] = 0.f;

    auto stageA = [&](int ks, int bf) {
        int idx = tid;
        int row = idx >> 2;
        int cb = (idx & 3) ^ ((row >> 1) & 3);
        gload16(wh + (size_t)(576 + row) * Cn + ks * 32 + cb * 8, Ah_ + bf * ASZ + idx * 8);
        gload16(wl + (size_t)(576 + row) * Cn + ks * 32 + cb * 8, Al_ + bf * ASZ + idx * 8);
        if (tid < 256) {
            idx = 512 + tid;
            row = idx >> 2;
            cb = (idx & 3) ^ ((row >> 1) & 3);
            gload16(wh + (size_t)(576 + row) * Cn + ks * 32 + cb * 8, Ah_ + bf * ASZ + idx * 8);
            gload16(wl + (size_t)(576 + row) * Cn + ks * 32 + cb * 8, Al_ + bf * ASZ + idx * 8);
        }
    };

    stageA(0, 0);
    __syncthreads();                     // A(0) drained
    for (int ks = 0; ks < 6; ++ks) {
        if (ks < 5) stageA(ks + 1, (ks + 1) & 1);   // issue early, other buffer
        {
            const int bf = ks & 1;
            #pragma unroll
            for (int kh = 0; kh < 2; ++kh) {
                const int cbb = kh * 2 + (l >> 5);
                bf16x8 ah[3], al[3];
                #pragma unroll
                for (int mf = 0; mf < 3; ++mf) {
                    int r = wm * 96 + mf * 32 + (l & 31);
                    int off = bf * ASZ + r * 32 + ((cbb ^ ((r >> 1) & 3)) << 3);
                    ah[mf] = *(const bf16x8*)&Ah_[off];
                    al[mf] = *(const bf16x8*)&Al_[off];
                }
                const int t = wn * 32 + (l & 31);
                const int o = t * 196 + ks * 32 + cbb * 8;
                union { uint2 q[2]; bf16x8 v; } bh, bl;
                bh.q[0] = *(const uint2*)&Yh_[o];
                bh.q[1] = *(const uint2*)&Yh_[o + 4];
                bl.q[0] = *(const uint2*)&Yl_[o];
                bl.q[1] = *(const uint2*)&Yl_[o + 4];
                #pragma unroll
                for (int mf = 0; mf < 3; ++mf) {
                    acc[mf] = __builtin_amdgcn_mfma_f32_32x32x16_bf16(ah[mf], bh.v, acc[mf], 0, 0, 0);
                    acc[mf] = __builtin_amdgcn_mfma_f32_32x32x16_bf16(ah[mf], bl.v, acc[mf], 0, 0, 0);
                    acc[mf] = __builtin_amdgcn_mfma_f32_32x32x16_bf16(al[mf], bh.v, acc[mf], 0, 0, 0);
                }
            }
        }
        __syncthreads();                 // A(ks+1) drained + readers done
    }

    #pragma unroll
    for (int mf = 0; mf < 3; ++mf) {
        const int col = t0 + wn * 32 + (l & 31);
        #pragma unroll
        for (int r = 0; r < 16; ++r) {
            int row = wm * 96 + mf * 32 + (r & 3) + 8 * (r >> 2) + 4 * (l >> 5);
            out[((size_t)b * Cn + row) * Tn + col] = acc[mf][r];
        }
    }
}

// ---------------------------------------------------------------------------
extern "C" void kernel_launch(void* const* d_in, const int* in_sizes, int n_in,
                              void* d_out, int out_size, void* d_ws, size_t ws_size,
                              hipStream_t stream) {
    const float* x        = (const float*)d_in[0];
    const float* w_key    = (const float*)d_in[1];
    const float* w_value  = (const float*)d_in[2];
    const float* w_recept = (const float*)d_in[3];
    const float* w_out    = (const float*)d_in[4];
    const float* decay    = (const float*)d_in[5];
    const float* boost    = (const float*)d_in[6];
    const float* alpha    = (const float*)d_in[7];
    const float* dw1      = (const float*)d_in[8];
    const float* dw3      = (const float*)d_in[9];
    const float* dw5      = (const float*)d_in[10];

    const size_t S = (size_t)Bn * Cn * Tn;   // 6291456 elements
    u16* R0 = (u16*)d_ws;                    // 2S u16 each region
    u16* R1 = R0 + 2 * S;
    u16* R2 = R1 + 2 * S;
    u16* whp = R2 + 2 * S;                   // stacked weights hi (4*36864)
    u16* wlp = whp + 4 * 36864;

    u16* xs_hi = R0;        u16* xs_lo = R0 + S;      // omni out / proj in
    float* kb  = (float*)R1;                          // proj out
    float* vb  = (float*)R2;
    float* srl = (float*)d_out;                       // scratch until wkv_out
    float4* states = (float4*)R0;                     // after xs dead (6.3 MB)
    float* out = (float*)d_out;

    // blocks 1536..1727 also perform the weight hi/lo split
    omni_kernel<<<dim3(1536 + 192), 256, 0, stream>>>(x, alpha, dw1, dw3, dw5,
                                                      w_key, w_value, w_recept, w_out,
                                                      xs_hi, xs_lo, whp, wlp);

    gemm_proj<<<dim3(32, 3, 8), 256, 0, stream>>>(whp, wlp, xs_hi, xs_lo, kb, vb, srl);

    wkv_stats<<<dim3(Bn * Cn), 256, 0, stream>>>(kb, vb, decay, states);

    wkv_out<<<dim3(32, 8), 512, 0, stream>>>(kb, vb, srl, states, decay, boost,
                                             whp, wlp, out);
}

// Round 17
// 110.411 us; speedup vs baseline: 1.1190x; 1.1190x over previous
//
#include <hip/hip_runtime.h>
#include <math.h>

#define Cn 192
#define Bn 8
#define Tn 4096
#define HW 64

typedef unsigned short u16;
typedef unsigned int u32;
typedef __attribute__((ext_vector_type(8))) __bf16 bf16x8;
typedef __attribute__((ext_vector_type(16))) float f32x16;

__device__ __forceinline__ void gload16(const void* g, void* l) {
    __builtin_amdgcn_global_load_lds(
        (const __attribute__((address_space(1))) void*)g,
        (__attribute__((address_space(3))) void*)l, 16, 0, 0);
}

__device__ __forceinline__ void split_bf16(float x, u16 &h, u16 &l) {
    u32 u = __float_as_uint(x);
    u32 uh = (u + 0x7FFFu + ((u >> 16) & 1u)) & 0xFFFF0000u;
    h = (u16)(uh >> 16);
    float r = x - __uint_as_float(uh);
    u32 ur = __float_as_uint(r);
    l = (u16)((ur + 0x7FFFu + ((ur >> 16) & 1u)) >> 16);
}

// ---------------------------------------------------------------------------
// Kernel 1: omni_shift (fused 25-tap depthwise conv) -> split bf16 hi/lo out.
// Blocks >= 1536 perform the weight hi/lo split (fused to save a dispatch).
// ---------------------------------------------------------------------------
__global__ __launch_bounds__(256) void omni_kernel(const float* __restrict__ x,
                                                   const float* __restrict__ alpha,
                                                   const float* __restrict__ dw1,
                                                   const float* __restrict__ dw3,
                                                   const float* __restrict__ dw5,
                                                   const float* __restrict__ Wk,
                                                   const float* __restrict__ Wv,
                                                   const float* __restrict__ Wr,
                                                   const float* __restrict__ Wo,
                                                   u16* __restrict__ xhi,
                                                   u16* __restrict__ xlo,
                                                   u16* __restrict__ wh,
                                                   u16* __restrict__ wl) {
    const int tid = threadIdx.x;
    if (blockIdx.x >= 1536) {
        const int base = (blockIdx.x - 1536) * 768;
        #pragma unroll
        for (int jj = 0; jj < 3; ++jj) {
            int idx = base + jj * 256 + tid;
            int mat = idx / 36864;
            int off = idx - mat * 36864;
            const float* src = (mat == 0) ? Wk : (mat == 1) ? Wv : (mat == 2) ? Wr : Wo;
            u16 h, l;
            split_bf16(src[off], h, l);
            wh[idx] = h;
            wl[idx] = l;
        }
        return;
    }

    const int plane = blockIdx.x;          // b*C + c
    const int c = plane % Cn;
    const float* xin = x + (size_t)plane * Tn;
    u16* oh = xhi + (size_t)plane * Tn;
    u16* ol = xlo + (size_t)plane * Tn;

    __shared__ float tile[68 * 68];
    __shared__ float wk[25];

    if (tid == 0) {
        const float a0 = alpha[0], a1 = alpha[1], a2 = alpha[2], a3 = alpha[3];
        #pragma unroll
        for (int j = 0; j < 25; ++j) wk[j] = a3 * dw5[c * 25 + j];
        #pragma unroll
        for (int dy = 0; dy < 3; ++dy)
            #pragma unroll
            for (int dx = 0; dx < 3; ++dx)
                wk[(dy + 1) * 5 + (dx + 1)] += a2 * dw3[c * 9 + dy * 3 + dx];
        wk[12] += a1 * dw1[c] + a0;
    }
    for (int i = tid; i < 68 * 68; i += 256) {
        int r = i / 68, cc = i - r * 68;
        int gy = r - 2, gx = cc - 2;
        float v = 0.f;
        if (gy >= 0 && gy < HW && gx >= 0 && gx < HW) v = xin[gy * HW + gx];
        tile[i] = v;
    }
    __syncthreads();

    const int py = tid >> 3;          // 0..31
    const int px0 = (tid & 7) << 3;   // 0,8,..,56

    #pragma unroll
    for (int half = 0; half < 2; ++half) {
        const int y = py + half * 32;
        float row[5][12];
        #pragma unroll
        for (int dy = 0; dy < 5; ++dy) {
            const float4* rp = (const float4*)&tile[(y + dy) * 68 + px0];
            float4 r0 = rp[0], r1 = rp[1], r2 = rp[2];
            row[dy][0] = r0.x; row[dy][1] = r0.y; row[dy][2]  = r0.z; row[dy][3]  = r0.w;
            row[dy][4] = r1.x; row[dy][5] = r1.y; row[dy][6]  = r1.z; row[dy][7]  = r1.w;
            row[dy][8] = r2.x; row[dy][9] = r2.y; row[dy][10] = r2.z; row[dy][11] = r2.w;
        }
        u32 ph[4], pl[4];
        #pragma unroll
        for (int jj = 0; jj < 8; ++jj) {
            float acc = 0.f;
            #pragma unroll
            for (int dy = 0; dy < 5; ++dy)
                #pragma unroll
                for (int dx = 0; dx < 5; ++dx)
                    acc = fmaf(row[dy][jj + dx], wk[dy * 5 + dx], acc);
            u16 h, l2;
            split_bf16(acc, h, l2);
            if (jj & 1) { ph[jj >> 1] |= ((u32)h) << 16; pl[jj >> 1] |= ((u32)l2) << 16; }
            else        { ph[jj >> 1] = h;               pl[jj >> 1] = l2; }
        }
        *(uint4*)&oh[y * 64 + px0] = make_uint4(ph[0], ph[1], ph[2], ph[3]);
        *(uint4*)&ol[y * 64 + px0] = make_uint4(pl[0], pl[1], pl[2], pl[3]);
    }
}

// ---------------------------------------------------------------------------
// Kernel 2: fused k/v/sr projection GEMM (R10/R15-measured best: t-tile 128,
// 43 KB pool, NO in-kernel summary, terminates with stores in flight).
// Grid reordered to (mt, t-tile, b) so neighboring blocks share the xs B-tile
// in L2 (pure index remap, numerics identical).
// ---------------------------------------------------------------------------
__global__ __launch_bounds__(256) void gemm_proj(const u16* __restrict__ wh,
                                                 const u16* __restrict__ wl,
                                                 const u16* __restrict__ Xh,
                                                 const u16* __restrict__ Xl,
                                                 float* __restrict__ O0,
                                                 float* __restrict__ O1,
                                                 float* __restrict__ O2) {
    __shared__ u16 Ah_[3 * 64 * 32], Al_[3 * 64 * 32];
    __shared__ u16 Bh_[128 * 36], Bl_[128 * 36];

    const int tid  = threadIdx.x;
    const int l    = tid & 63;
    const int wave = tid >> 6;
    const int wm   = wave >> 1, wn = wave & 1;
    const int m0   = blockIdx.x * 64;          // mt innermost
    const int t0   = blockIdx.y * 128;
    const size_t xb = (size_t)blockIdx.z * Cn * Tn;
    const int cpair = tid & 15;         // c-pair 0..15
    const int toct  = tid >> 4;         // t-oct 0..15

    f32x16 acc[3][2];
    #pragma unroll
    for (int m = 0; m < 3; ++m)
        #pragma unroll
        for (int nf = 0; nf < 2; ++nf)
            #pragma unroll
            for (int r = 0; r < 16; ++r) acc[m][nf][r] = 0.f;

    uint4 rh0, rh1, rl0, rl1;           // B reg-stage (one K-step)

    auto loadB = [&](int k0) {
        size_t g = xb + (size_t)(k0 + 2 * cpair) * Tn + t0 + toct * 8;
        rh0 = *(const uint4*)&Xh[g];
        rh1 = *(const uint4*)&Xh[g + Tn];
        rl0 = *(const uint4*)&Xl[g];
        rl1 = *(const uint4*)&Xl[g + Tn];
    };
    auto writeB = [&]() {
        const u32 h0[4] = {rh0.x, rh0.y, rh0.z, rh0.w};
        const u32 h1[4] = {rh1.x, rh1.y, rh1.z, rh1.w};
        const u32 l0[4] = {rl0.x, rl0.y, rl0.z, rl0.w};
        const u32 l1[4] = {rl1.x, rl1.y, rl1.z, rl1.w};
        #pragma unroll
        for (int j = 0; j < 8; ++j) {
            int t = toct * 8 + j;
            int sh = 16 * (j & 1);
            u32 a = (h0[j >> 1] >> sh) & 0xFFFFu;
            u32 b = (h1[j >> 1] >> sh) & 0xFFFFu;
            *(u32*)&Bh_[t * 36 + 2 * cpair] = a | (b << 16);
            u32 c = (l0[j >> 1] >> sh) & 0xFFFFu;
            u32 d = (l1[j >> 1] >> sh) & 0xFFFFu;
            *(u32*)&Bl_[t * 36 + 2 * cpair] = c | (d << 16);
        }
    };
    auto stageA = [&](int k0) {
        #pragma unroll
        for (int i = 0; i < 3; ++i) {
            int idx = i * 256 + tid;
            int row = idx >> 2;
            int cb  = (idx & 3) ^ ((row >> 1) & 3);
            int grow = (row >> 6) * 192 + m0 + (row & 63);
            gload16(wh + (size_t)grow * Cn + k0 + cb * 8, Ah_ + idx * 8);
            gload16(wl + (size_t)grow * Cn + k0 + cb * 8, Al_ + idx * 8);
        }
    };
    auto compute = [&]() {
        #pragma unroll
        for (int kh = 0; kh < 2; ++kh) {
            const int cbb = kh * 2 + (l >> 5);
            bf16x8 ah[3], al[3];
            #pragma unroll
            for (int m = 0; m < 3; ++m) {
                int r = m * 64 + wm * 32 + (l & 31);
                int off = r * 32 + ((cbb ^ ((r >> 1) & 3)) << 3);
                ah[m] = *(const bf16x8*)&Ah_[off];
                al[m] = *(const bf16x8*)&Al_[off];
            }
            #pragma unroll
            for (int nf = 0; nf < 2; ++nf) {
                int t = wn * 64 + nf * 32 + (l & 31);
                int o = t * 36 + cbb * 8;
                union { uint2 q[2]; bf16x8 v; } th, tl2;
                th.q[0]  = *(const uint2*)&Bh_[o];
                th.q[1]  = *(const uint2*)&Bh_[o + 4];
                tl2.q[0] = *(const uint2*)&Bl_[o];
                tl2.q[1] = *(const uint2*)&Bl_[o + 4];
                #pragma unroll
                for (int m = 0; m < 3; ++m) {
                    acc[m][nf] = __builtin_amdgcn_mfma_f32_32x32x16_bf16(ah[m], th.v,  acc[m][nf], 0, 0, 0);
                    acc[m][nf] = __builtin_amdgcn_mfma_f32_32x32x16_bf16(ah[m], tl2.v, acc[m][nf], 0, 0, 0);
                    acc[m][nf] = __builtin_amdgcn_mfma_f32_32x32x16_bf16(al[m], th.v,  acc[m][nf], 0, 0, 0);
                }
            }
        }
    };

    loadB(0);
    stageA(0);
    writeB();                           // waits vmcnt on B regs
    __syncthreads();                    // drains A gloads + B writes visible
    loadB(32);
    for (int ks = 0; ks < 6; ++ks) {
        compute();
        if (ks < 5) {
            __syncthreads();            // readers done with LDS
            writeB();                   // B regs from prefetch
            stageA((ks + 1) * 32);
            __syncthreads();            // A drained + B writes visible
            if (ks < 4) loadB((ks + 2) * 32);
        }
    }

    // ---- epilogue: global stores of k, v, sr (kernel ends with stores in flight)
    float* Os[3] = {O0, O1, O2};
    #pragma unroll
    for (int m = 0; m < 3; ++m) {
        float* O = Os[m] + (size_t)blockIdx.z * Cn * Tn;
        #pragma unroll
        for (int nf = 0; nf < 2; ++nf) {
            int col = t0 + wn * 64 + nf * 32 + (l & 31);
            #pragma unroll
            for (int r = 0; r < 16; ++r) {
                int row = m0 + wm * 32 + (r & 3) + 8 * (r >> 2) + 4 * (l >> 5);
                O[(size_t)row * Tn + col] = acc[m][nf][r];
            }
        }
    }
}

// ---------------------------------------------------------------------------
// Kernel 3: wkv_stats — per-(b,d) row: per-16-chunk summaries from k,v
// (L3-hot re-read) + cross-chunk Hillis-Steele scan -> exclusive states.
// ---------------------------------------------------------------------------
__global__ __launch_bounds__(256) void wkv_stats(const float* __restrict__ kg,
                                                 const float* __restrict__ vg,
                                                 const float* __restrict__ decay,
                                                 float4* __restrict__ states) {
    const int row = blockIdx.x;       // b*C + d
    const int d = row % Cn;
    const float* kr = kg + (size_t)row * Tn;
    const float* vr = vg + (size_t)row * Tn;

    const int tid = threadIdx.x;
    const int t0 = tid * 16;

    float kk[16], vv[16];
    #pragma unroll
    for (int j = 0; j < 16; j += 4) {
        *(float4*)&kk[j] = *(const float4*)&kr[t0 + j];
        *(float4*)&vv[j] = *(const float4*)&vr[t0 + j];
    }

    const float ww = decay[d] * (1.0f / (float)Tn);
    const float lam = expf(-ww);
    const float lam16 = expf(-16.0f * ww);

    float a[16];
    #pragma unroll
    for (int j = 0; j < 16; ++j) a[j] = expf(kk[j]);

    float SN = 0.f, SD = 0.f;
    #pragma unroll
    for (int j = 0; j < 16; ++j) { SN = fmaf(lam, SN, a[j] * vv[j]); SD = fmaf(lam, SD, a[j]); }
    float BN = 0.f, BD = 0.f;
    #pragma unroll
    for (int j = 15; j >= 0; --j) { BN = fmaf(lam, BN, a[j] * vv[j]); BD = fmaf(lam, BD, a[j]); }

    __shared__ float sN[2][256], sD[2][256];

    sN[0][tid] = SN; sD[0][tid] = SD;
    __syncthreads();
    int src = 0;
    float f = lam16;
    for (int o = 1; o < 256; o <<= 1) {
        float nN = sN[src][tid], nD = sD[src][tid];
        if (tid >= o) { nN = fmaf(f, sN[src][tid - o], nN); nD = fmaf(f, sD[src][tid - o], nD); }
        sN[src ^ 1][tid] = nN; sD[src ^ 1][tid] = nD;
        __syncthreads();
        src ^= 1; f = f * f;
    }
    const float CfN = (tid > 0) ? sN[src][tid - 1] : 0.f;
    const float CfD = (tid > 0) ? sD[src][tid - 1] : 0.f;
    __syncthreads();

    sN[0][tid] = BN; sD[0][tid] = BD;
    __syncthreads();
    src = 0; f = lam16;
    for (int o = 1; o < 256; o <<= 1) {
        float nN = sN[src][tid], nD = sD[src][tid];
        if (tid + o < 256) { nN = fmaf(f, sN[src][tid + o], nN); nD = fmaf(f, sD[src][tid + o], nD); }
        sN[src ^ 1][tid] = nN; sD[src ^ 1][tid] = nD;
        __syncthreads();
        src ^= 1; f = f * f;
    }
    const float CbN = (tid < 255) ? sN[src][tid + 1] : 0.f;
    const float CbD = (tid < 255) ? sD[src][tid + 1] : 0.f;

    const int b = row / Cn;
    states[((size_t)(b * 256 + tid)) * Cn + d] = make_float4(CfN, CfD, CbN, CbD);
}

// ---------------------------------------------------------------------------
// Kernel 4: wkv_out — block (b, t-tile 128) x all 192 d, 512 threads,
// DOUBLE-BUFFERED A staging (R14/R15-measured best): stage A(ks+1) issued
// before compute(ks); L2-hot drain hides under the MFMAs; one barrier per
// K-step. LDS ~146 KB, 1 block/CU.
// ---------------------------------------------------------------------------
__global__ __launch_bounds__(512) void wkv_out(const float* __restrict__ kb,
                                               const float* __restrict__ vb,
                                               const float* __restrict__ srl,
                                               const float4* __restrict__ states,
                                               const float* __restrict__ decay,
                                               const float* __restrict__ boost,
                                               const u16* __restrict__ wh,
                                               const u16* __restrict__ wl,
                                               float* __restrict__ out) {
    constexpr int ASZ = 192 * 32;      // u16 per A buffer (hi or lo)
    __shared__ u16 Yh_[128 * 196], Yl_[128 * 196];
    __shared__ u16 Ah_[2 * ASZ], Al_[2 * ASZ];

    const int tid = threadIdx.x;
    const int b = blockIdx.y;
    const int t0 = blockIdx.x * 128;

    // ---- combine phase: 1536 (d, chunk) tasks over 512 threads ----
    for (int pass = 0; pass < 3; ++pass) {
        const int task = pass * 512 + tid;
        const int d  = task % Cn;
        const int ch = task / Cn;          // 0..7
        const size_t rbase = ((size_t)b * Cn + d) * Tn + t0 + ch * 16;
        const float4 st = states[((size_t)(b * 256 + (t0 >> 4) + ch)) * Cn + d];
        const float ww = decay[d] * (1.0f / (float)Tn);
        const float lam = expf(-ww);
        const float u = boost[d] * (1.0f / (float)Tn);

        float kk[16], vv[16], sl[16];
        #pragma unroll
        for (int j = 0; j < 16; j += 4) {
            *(float4*)&kk[j] = *(const float4*)&kb[rbase + j];
            *(float4*)&vv[j] = *(const float4*)&vb[rbase + j];
            *(float4*)&sl[j] = *(const float4*)&srl[rbase + j];
        }
        float a[16];
        #pragma unroll
        for (int j = 0; j < 16; ++j) a[j] = expf(kk[j]);

        float fN[16], fD[16];
        float cN = st.x, cD = st.y;
        #pragma unroll
        for (int j = 0; j < 16; ++j) {
            fN[j] = cN; fD[j] = cD;
            cN = fmaf(lam, cN, a[j] * vv[j]);
            cD = fmaf(lam, cD, a[j]);
        }
        float bN = st.z, bD = st.w;
        #pragma unroll
        for (int j = 15; j >= 0; --j) {
            const float es = expf(u + kk[j]);
            const float y = (fN[j] + bN + es * vv[j]) / (fD[j] + bD + es);
            const float sig = 1.0f / (1.0f + expf(-sl[j]));
            u16 h, l2;
            split_bf16(sig * y, h, l2);
            const int t = ch * 16 + j;
            Yh_[t * 196 + d] = h;
            Yl_[t * 196 + d] = l2;
            bN = fmaf(lam, bN, a[j] * vv[j]);
            bD = fmaf(lam, bD, a[j]);
        }
    }
    __syncthreads();

    // ---- out-projection GEMM: M=192 (w_out rows), N=128 (t), K=192 (d) ----
    const int l = tid & 63;
    const int wave = tid >> 6;
    const int wm = wave >> 2;           // 0..1  (96 M-rows each)
    const int wn = wave & 3;            // 0..3  (32 t-cols each)

    f32x16 acc[3];
    #pragma unroll
    for (int mf = 0; mf < 3; ++mf)
        #pragma unroll
        for (int r = 0; r < 16; ++r) acc[mf][r] = 0.f;

    auto stageA = [&](int ks, int bf) {
        int idx = tid;
        int row = idx >> 2;
        int cb = (idx & 3) ^ ((row >> 1) & 3);
        gload16(wh + (size_t)(576 + row) * Cn + ks * 32 + cb * 8, Ah_ + bf * ASZ + idx * 8);
        gload16(wl + (size_t)(576 + row) * Cn + ks * 32 + cb * 8, Al_ + bf * ASZ + idx * 8);
        if (tid < 256) {
            idx = 512 + tid;
            row = idx >> 2;
            cb = (idx & 3) ^ ((row >> 1) & 3);
            gload16(wh + (size_t)(576 + row) * Cn + ks * 32 + cb * 8, Ah_ + bf * ASZ + idx * 8);
            gload16(wl + (size_t)(576 + row) * Cn + ks * 32 + cb * 8, Al_ + bf * ASZ + idx * 8);
        }
    };

    stageA(0, 0);
    __syncthreads();                     // A(0) drained
    for (int ks = 0; ks < 6; ++ks) {
        if (ks < 5) stageA(ks + 1, (ks + 1) & 1);   // issue early, other buffer
        {
            const int bf = ks & 1;
            #pragma unroll
            for (int kh = 0; kh < 2; ++kh) {
                const int cbb = kh * 2 + (l >> 5);
                bf16x8 ah[3], al[3];
                #pragma unroll
                for (int mf = 0; mf < 3; ++mf) {
                    int r = wm * 96 + mf * 32 + (l & 31);
                    int off = bf * ASZ + r * 32 + ((cbb ^ ((r >> 1) & 3)) << 3);
                    ah[mf] = *(const bf16x8*)&Ah_[off];
                    al[mf] = *(const bf16x8*)&Al_[off];
                }
                const int t = wn * 32 + (l & 31);
                const int o = t * 196 + ks * 32 + cbb * 8;
                union { uint2 q[2]; bf16x8 v; } bh, bl;
                bh.q[0] = *(const uint2*)&Yh_[o];
                bh.q[1] = *(const uint2*)&Yh_[o + 4];
                bl.q[0] = *(const uint2*)&Yl_[o];
                bl.q[1] = *(const uint2*)&Yl_[o + 4];
                #pragma unroll
                for (int mf = 0; mf < 3; ++mf) {
                    acc[mf] = __builtin_amdgcn_mfma_f32_32x32x16_bf16(ah[mf], bh.v, acc[mf], 0, 0, 0);
                    acc[mf] = __builtin_amdgcn_mfma_f32_32x32x16_bf16(ah[mf], bl.v, acc[mf], 0, 0, 0);
                    acc[mf] = __builtin_amdgcn_mfma_f32_32x32x16_bf16(al[mf], bh.v, acc[mf], 0, 0, 0);
                }
            }
        }
        __syncthreads();                 // A(ks+1) drained + readers done
    }

    #pragma unroll
    for (int mf = 0; mf < 3; ++mf) {
        const int col = t0 + wn * 32 + (l & 31);
        #pragma unroll
        for (int r = 0; r < 16; ++r) {
            int row = wm * 96 + mf * 32 + (r & 3) + 8 * (r >> 2) + 4 * (l >> 5);
            out[((size_t)b * Cn + row) * Tn + col] = acc[mf][r];
        }
    }
}

// ---------------------------------------------------------------------------
extern "C" void kernel_launch(void* const* d_in, const int* in_sizes, int n_in,
                              void* d_out, int out_size, void* d_ws, size_t ws_size,
                              hipStream_t stream) {
    const float* x        = (const float*)d_in[0];
    const float* w_key    = (const float*)d_in[1];
    const float* w_value  = (const float*)d_in[2];
    const float* w_recept = (const float*)d_in[3];
    const float* w_out    = (const float*)d_in[4];
    const float* decay    = (const float*)d_in[5];
    const float* boost    = (const float*)d_in[6];
    const float* alpha    = (const float*)d_in[7];
    const float* dw1      = (const float*)d_in[8];
    const float* dw3      = (const float*)d_in[9];
    const float* dw5      = (const float*)d_in[10];

    const size_t S = (size_t)Bn * Cn * Tn;   // 6291456 elements
    u16* R0 = (u16*)d_ws;                    // 2S u16 each region
    u16* R1 = R0 + 2 * S;
    u16* R2 = R1 + 2 * S;
    u16* whp = R2 + 2 * S;                   // stacked weights hi (4*36864)
    u16* wlp = whp + 4 * 36864;

    u16* xs_hi = R0;        u16* xs_lo = R0 + S;      // omni out / proj in
    float* kb  = (float*)R1;                          // proj out
    float* vb  = (float*)R2;
    float* srl = (float*)d_out;                       // scratch until wkv_out
    float4* states = (float4*)R0;                     // after xs dead (6.3 MB)
    float* out = (float*)d_out;

    // blocks 1536..1727 also perform the weight hi/lo split
    omni_kernel<<<dim3(1536 + 192), 256, 0, stream>>>(x, alpha, dw1, dw3, dw5,
                                                      w_key, w_value, w_recept, w_out,
                                                      xs_hi, xs_lo, whp, wlp);

    gemm_proj<<<dim3(3, 32, 8), 256, 0, stream>>>(whp, wlp, xs_hi, xs_lo, kb, vb, srl);

    wkv_stats<<<dim3(Bn * Cn), 256, 0, stream>>>(kb, vb, decay, states);

    wkv_out<<<dim3(32, 8), 512, 0, stream>>>(kb, vb, srl, states, decay, boost,
                                             whp, wlp, out);
}

// Round 18
// 107.736 us; speedup vs baseline: 1.1467x; 1.0248x over previous
//
#include <hip/hip_runtime.h>
#include <math.h>

#define Cn 192
#define Bn 8
#define Tn 4096
#define HW 64

typedef unsigned short u16;
typedef unsigned int u32;
typedef __attribute__((ext_vector_type(8))) __bf16 bf16x8;
typedef __attribute__((ext_vector_type(16))) float f32x16;

__device__ __forceinline__ void gload16(const void* g, void* l) {
    __builtin_amdgcn_global_load_lds(
        (const __attribute__((address_space(1))) void*)g,
        (__attribute__((address_space(3))) void*)l, 16, 0, 0);
}

__device__ __forceinline__ void split_bf16(float x, u16 &h, u16 &l) {
    u32 u = __float_as_uint(x);
    u32 uh = (u + 0x7FFFu + ((u >> 16) & 1u)) & 0xFFFF0000u;
    h = (u16)(uh >> 16);
    float r = x - __uint_as_float(uh);
    u32 ur = __float_as_uint(r);
    l = (u16)((ur + 0x7FFFu + ((ur >> 16) & 1u)) >> 16);
}

// ---------------------------------------------------------------------------
// Kernel 1: omni_shift (fused 25-tap depthwise conv) -> split bf16 hi/lo out.
// Blocks >= 1536 perform the weight hi/lo split (fused to save a dispatch).
// ---------------------------------------------------------------------------
__global__ __launch_bounds__(256) void omni_kernel(const float* __restrict__ x,
                                                   const float* __restrict__ alpha,
                                                   const float* __restrict__ dw1,
                                                   const float* __restrict__ dw3,
                                                   const float* __restrict__ dw5,
                                                   const float* __restrict__ Wk,
                                                   const float* __restrict__ Wv,
                                                   const float* __restrict__ Wr,
                                                   const float* __restrict__ Wo,
                                                   u16* __restrict__ xhi,
                                                   u16* __restrict__ xlo,
                                                   u16* __restrict__ wh,
                                                   u16* __restrict__ wl) {
    const int tid = threadIdx.x;
    if (blockIdx.x >= 1536) {
        const int base = (blockIdx.x - 1536) * 768;
        #pragma unroll
        for (int jj = 0; jj < 3; ++jj) {
            int idx = base + jj * 256 + tid;
            int mat = idx / 36864;
            int off = idx - mat * 36864;
            const float* src = (mat == 0) ? Wk : (mat == 1) ? Wv : (mat == 2) ? Wr : Wo;
            u16 h, l;
            split_bf16(src[off], h, l);
            wh[idx] = h;
            wl[idx] = l;
        }
        return;
    }

    const int plane = blockIdx.x;          // b*C + c
    const int c = plane % Cn;
    const float* xin = x + (size_t)plane * Tn;
    u16* oh = xhi + (size_t)plane * Tn;
    u16* ol = xlo + (size_t)plane * Tn;

    __shared__ float tile[68 * 68];
    __shared__ float wk[25];

    if (tid == 0) {
        const float a0 = alpha[0], a1 = alpha[1], a2 = alpha[2], a3 = alpha[3];
        #pragma unroll
        for (int j = 0; j < 25; ++j) wk[j] = a3 * dw5[c * 25 + j];
        #pragma unroll
        for (int dy = 0; dy < 3; ++dy)
            #pragma unroll
            for (int dx = 0; dx < 3; ++dx)
                wk[(dy + 1) * 5 + (dx + 1)] += a2 * dw3[c * 9 + dy * 3 + dx];
        wk[12] += a1 * dw1[c] + a0;
    }
    for (int i = tid; i < 68 * 68; i += 256) {
        int r = i / 68, cc = i - r * 68;
        int gy = r - 2, gx = cc - 2;
        float v = 0.f;
        if (gy >= 0 && gy < HW && gx >= 0 && gx < HW) v = xin[gy * HW + gx];
        tile[i] = v;
    }
    __syncthreads();

    const int py = tid >> 3;          // 0..31
    const int px0 = (tid & 7) << 3;   // 0,8,..,56

    #pragma unroll
    for (int half = 0; half < 2; ++half) {
        const int y = py + half * 32;
        float row[5][12];
        #pragma unroll
        for (int dy = 0; dy < 5; ++dy) {
            const float4* rp = (const float4*)&tile[(y + dy) * 68 + px0];
            float4 r0 = rp[0], r1 = rp[1], r2 = rp[2];
            row[dy][0] = r0.x; row[dy][1] = r0.y; row[dy][2]  = r0.z; row[dy][3]  = r0.w;
            row[dy][4] = r1.x; row[dy][5] = r1.y; row[dy][6]  = r1.z; row[dy][7]  = r1.w;
            row[dy][8] = r2.x; row[dy][9] = r2.y; row[dy][10] = r2.z; row[dy][11] = r2.w;
        }
        u32 ph[4], pl[4];
        #pragma unroll
        for (int jj = 0; jj < 8; ++jj) {
            float acc = 0.f;
            #pragma unroll
            for (int dy = 0; dy < 5; ++dy)
                #pragma unroll
                for (int dx = 0; dx < 5; ++dx)
                    acc = fmaf(row[dy][jj + dx], wk[dy * 5 + dx], acc);
            u16 h, l2;
            split_bf16(acc, h, l2);
            if (jj & 1) { ph[jj >> 1] |= ((u32)h) << 16; pl[jj >> 1] |= ((u32)l2) << 16; }
            else        { ph[jj >> 1] = h;               pl[jj >> 1] = l2; }
        }
        *(uint4*)&oh[y * 64 + px0] = make_uint4(ph[0], ph[1], ph[2], ph[3]);
        *(uint4*)&ol[y * 64 + px0] = make_uint4(pl[0], pl[1], pl[2], pl[3]);
    }
}

// ---------------------------------------------------------------------------
// Kernel 2: fused k/v/sr projection GEMM (R10/R15-measured best: t-tile 128,
// 43 KB pool, NO in-kernel summary, terminates with stores in flight).
// ---------------------------------------------------------------------------
__global__ __launch_bounds__(256) void gemm_proj(const u16* __restrict__ wh,
                                                 const u16* __restrict__ wl,
                                                 const u16* __restrict__ Xh,
                                                 const u16* __restrict__ Xl,
                                                 float* __restrict__ O0,
                                                 float* __restrict__ O1,
                                                 float* __restrict__ O2) {
    __shared__ u16 Ah_[3 * 64 * 32], Al_[3 * 64 * 32];
    __shared__ u16 Bh_[128 * 36], Bl_[128 * 36];

    const int tid  = threadIdx.x;
    const int l    = tid & 63;
    const int wave = tid >> 6;
    const int wm   = wave >> 1, wn = wave & 1;
    const int m0   = blockIdx.y * 64;
    const int t0   = blockIdx.x * 128;
    const size_t xb = (size_t)blockIdx.z * Cn * Tn;
    const int cpair = tid & 15;         // c-pair 0..15
    const int toct  = tid >> 4;         // t-oct 0..15

    f32x16 acc[3][2];
    #pragma unroll
    for (int m = 0; m < 3; ++m)
        #pragma unroll
        for (int nf = 0; nf < 2; ++nf)
            #pragma unroll
            for (int r = 0; r < 16; ++r) acc[m][nf][r] = 0.f;

    uint4 rh0, rh1, rl0, rl1;           // B reg-stage (one K-step)

    auto loadB = [&](int k0) {
        size_t g = xb + (size_t)(k0 + 2 * cpair) * Tn + t0 + toct * 8;
        rh0 = *(const uint4*)&Xh[g];
        rh1 = *(const uint4*)&Xh[g + Tn];
        rl0 = *(const uint4*)&Xl[g];
        rl1 = *(const uint4*)&Xl[g + Tn];
    };
    auto writeB = [&]() {
        const u32 h0[4] = {rh0.x, rh0.y, rh0.z, rh0.w};
        const u32 h1[4] = {rh1.x, rh1.y, rh1.z, rh1.w};
        const u32 l0[4] = {rl0.x, rl0.y, rl0.z, rl0.w};
        const u32 l1[4] = {rl1.x, rl1.y, rl1.z, rl1.w};
        #pragma unroll
        for (int j = 0; j < 8; ++j) {
            int t = toct * 8 + j;
            int sh = 16 * (j & 1);
            u32 a = (h0[j >> 1] >> sh) & 0xFFFFu;
            u32 b = (h1[j >> 1] >> sh) & 0xFFFFu;
            *(u32*)&Bh_[t * 36 + 2 * cpair] = a | (b << 16);
            u32 c = (l0[j >> 1] >> sh) & 0xFFFFu;
            u32 d = (l1[j >> 1] >> sh) & 0xFFFFu;
            *(u32*)&Bl_[t * 36 + 2 * cpair] = c | (d << 16);
        }
    };
    auto stageA = [&](int k0) {
        #pragma unroll
        for (int i = 0; i < 3; ++i) {
            int idx = i * 256 + tid;
            int row = idx >> 2;
            int cb  = (idx & 3) ^ ((row >> 1) & 3);
            int grow = (row >> 6) * 192 + m0 + (row & 63);
            gload16(wh + (size_t)grow * Cn + k0 + cb * 8, Ah_ + idx * 8);
            gload16(wl + (size_t)grow * Cn + k0 + cb * 8, Al_ + idx * 8);
        }
    };
    auto compute = [&]() {
        #pragma unroll
        for (int kh = 0; kh < 2; ++kh) {
            const int cbb = kh * 2 + (l >> 5);
            bf16x8 ah[3], al[3];
            #pragma unroll
            for (int m = 0; m < 3; ++m) {
                int r = m * 64 + wm * 32 + (l & 31);
                int off = r * 32 + ((cbb ^ ((r >> 1) & 3)) << 3);
                ah[m] = *(const bf16x8*)&Ah_[off];
                al[m] = *(const bf16x8*)&Al_[off];
            }
            #pragma unroll
            for (int nf = 0; nf < 2; ++nf) {
                int t = wn * 64 + nf * 32 + (l & 31);
                int o = t * 36 + cbb * 8;
                union { uint2 q[2]; bf16x8 v; } th, tl2;
                th.q[0]  = *(const uint2*)&Bh_[o];
                th.q[1]  = *(const uint2*)&Bh_[o + 4];
                tl2.q[0] = *(const uint2*)&Bl_[o];
                tl2.q[1] = *(const uint2*)&Bl_[o + 4];
                #pragma unroll
                for (int m = 0; m < 3; ++m) {
                    acc[m][nf] = __builtin_amdgcn_mfma_f32_32x32x16_bf16(ah[m], th.v,  acc[m][nf], 0, 0, 0);
                    acc[m][nf] = __builtin_amdgcn_mfma_f32_32x32x16_bf16(ah[m], tl2.v, acc[m][nf], 0, 0, 0);
                    acc[m][nf] = __builtin_amdgcn_mfma_f32_32x32x16_bf16(al[m], th.v,  acc[m][nf], 0, 0, 0);
                }
            }
        }
    };

    loadB(0);
    stageA(0);
    writeB();                           // waits vmcnt on B regs
    __syncthreads();                    // drains A gloads + B writes visible
    loadB(32);
    for (int ks = 0; ks < 6; ++ks) {
        compute();
        if (ks < 5) {
            __syncthreads();            // readers done with LDS
            writeB();                   // B regs from prefetch
            stageA((ks + 1) * 32);
            __syncthreads();            // A drained + B writes visible
            if (ks < 4) loadB((ks + 2) * 32);
        }
    }

    // ---- epilogue: global stores of k, v, sr (kernel ends with stores in flight)
    float* Os[3] = {O0, O1, O2};
    #pragma unroll
    for (int m = 0; m < 3; ++m) {
        float* O = Os[m] + (size_t)blockIdx.z * Cn * Tn;
        #pragma unroll
        for (int nf = 0; nf < 2; ++nf) {
            int col = t0 + wn * 64 + nf * 32 + (l & 31);
            #pragma unroll
            for (int r = 0; r < 16; ++r) {
                int row = m0 + wm * 32 + (r & 3) + 8 * (r >> 2) + 4 * (l >> 5);
                O[(size_t)row * Tn + col] = acc[m][nf][r];
            }
        }
    }
}

// ---------------------------------------------------------------------------
// Kernel 3: wkv_stats — per-(b,d) row: per-16-chunk summaries from k,v
// (L3-hot re-read) + cross-chunk Hillis-Steele scan -> exclusive states.
// ---------------------------------------------------------------------------
__global__ __launch_bounds__(256) void wkv_stats(const float* __restrict__ kg,
                                                 const float* __restrict__ vg,
                                                 const float* __restrict__ decay,
                                                 float4* __restrict__ states) {
    const int row = blockIdx.x;       // b*C + d
    const int d = row % Cn;
    const float* kr = kg + (size_t)row * Tn;
    const float* vr = vg + (size_t)row * Tn;

    const int tid = threadIdx.x;
    const int t0 = tid * 16;

    float kk[16], vv[16];
    #pragma unroll
    for (int j = 0; j < 16; j += 4) {
        *(float4*)&kk[j] = *(const float4*)&kr[t0 + j];
        *(float4*)&vv[j] = *(const float4*)&vr[t0 + j];
    }

    const float ww = decay[d] * (1.0f / (float)Tn);
    const float lam = expf(-ww);
    const float lam16 = expf(-16.0f * ww);

    float a[16];
    #pragma unroll
    for (int j = 0; j < 16; ++j) a[j] = expf(kk[j]);

    float SN = 0.f, SD = 0.f;
    #pragma unroll
    for (int j = 0; j < 16; ++j) { SN = fmaf(lam, SN, a[j] * vv[j]); SD = fmaf(lam, SD, a[j]); }
    float BN = 0.f, BD = 0.f;
    #pragma unroll
    for (int j = 15; j >= 0; --j) { BN = fmaf(lam, BN, a[j] * vv[j]); BD = fmaf(lam, BD, a[j]); }

    __shared__ float sN[2][256], sD[2][256];

    sN[0][tid] = SN; sD[0][tid] = SD;
    __syncthreads();
    int src = 0;
    float f = lam16;
    for (int o = 1; o < 256; o <<= 1) {
        float nN = sN[src][tid], nD = sD[src][tid];
        if (tid >= o) { nN = fmaf(f, sN[src][tid - o], nN); nD = fmaf(f, sD[src][tid - o], nD); }
        sN[src ^ 1][tid] = nN; sD[src ^ 1][tid] = nD;
        __syncthreads();
        src ^= 1; f = f * f;
    }
    const float CfN = (tid > 0) ? sN[src][tid - 1] : 0.f;
    const float CfD = (tid > 0) ? sD[src][tid - 1] : 0.f;
    __syncthreads();

    sN[0][tid] = BN; sD[0][tid] = BD;
    __syncthreads();
    src = 0; f = lam16;
    for (int o = 1; o < 256; o <<= 1) {
        float nN = sN[src][tid], nD = sD[src][tid];
        if (tid + o < 256) { nN = fmaf(f, sN[src][tid + o], nN); nD = fmaf(f, sD[src][tid + o], nD); }
        sN[src ^ 1][tid] = nN; sD[src ^ 1][tid] = nD;
        __syncthreads();
        src ^= 1; f = f * f;
    }
    const float CbN = (tid < 255) ? sN[src][tid + 1] : 0.f;
    const float CbD = (tid < 255) ? sD[src][tid + 1] : 0.f;

    const int b = row / Cn;
    states[((size_t)(b * 256 + tid)) * Cn + d] = make_float4(CfN, CfD, CbN, CbD);
}

// ---------------------------------------------------------------------------
// Kernel 4: wkv_out — block (b, t-tile 128) x all 192 d, 512 threads,
// DOUBLE-BUFFERED A staging (R14/R15-measured best): stage A(ks+1) issued
// before compute(ks); L2-hot drain hides under the MFMAs; one barrier per
// K-step. LDS ~146 KB, 1 block/CU.
// ---------------------------------------------------------------------------
__global__ __launch_bounds__(512) void wkv_out(const float* __restrict__ kb,
                                               const float* __restrict__ vb,
                                               const float* __restrict__ srl,
                                               const float4* __restrict__ states,
                                               const float* __restrict__ decay,
                                               const float* __restrict__ boost,
                                               const u16* __restrict__ wh,
                                               const u16* __restrict__ wl,
                                               float* __restrict__ out) {
    constexpr int ASZ = 192 * 32;      // u16 per A buffer (hi or lo)
    __shared__ u16 Yh_[128 * 196], Yl_[128 * 196];
    __shared__ u16 Ah_[2 * ASZ], Al_[2 * ASZ];

    const int tid = threadIdx.x;
    const int b = blockIdx.y;
    const int t0 = blockIdx.x * 128;

    // ---- combine phase: 1536 (d, chunk) tasks over 512 threads ----
    for (int pass = 0; pass < 3; ++pass) {
        const int task = pass * 512 + tid;
        const int d  = task % Cn;
        const int ch = task / Cn;          // 0..7
        const size_t rbase = ((size_t)b * Cn + d) * Tn + t0 + ch * 16;
        const float4 st = states[((size_t)(b * 256 + (t0 >> 4) + ch)) * Cn + d];
        const float ww = decay[d] * (1.0f / (float)Tn);
        const float lam = expf(-ww);
        const float u = boost[d] * (1.0f / (float)Tn);

        float kk[16], vv[16], sl[16];
        #pragma unroll
        for (int j = 0; j < 16; j += 4) {
            *(float4*)&kk[j] = *(const float4*)&kb[rbase + j];
            *(float4*)&vv[j] = *(const float4*)&vb[rbase + j];
            *(float4*)&sl[j] = *(const float4*)&srl[rbase + j];
        }
        float a[16];
        #pragma unroll
        for (int j = 0; j < 16; ++j) a[j] = expf(kk[j]);

        float fN[16], fD[16];
        float cN = st.x, cD = st.y;
        #pragma unroll
        for (int j = 0; j < 16; ++j) {
            fN[j] = cN; fD[j] = cD;
            cN = fmaf(lam, cN, a[j] * vv[j]);
            cD = fmaf(lam, cD, a[j]);
        }
        float bN = st.z, bD = st.w;
        #pragma unroll
        for (int j = 15; j >= 0; --j) {
            const float es = expf(u + kk[j]);
            const float y = (fN[j] + bN + es * vv[j]) / (fD[j] + bD + es);
            const float sig = 1.0f / (1.0f + expf(-sl[j]));
            u16 h, l2;
            split_bf16(sig * y, h, l2);
            const int t = ch * 16 + j;
            Yh_[t * 196 + d] = h;
            Yl_[t * 196 + d] = l2;
            bN = fmaf(lam, bN, a[j] * vv[j]);
            bD = fmaf(lam, bD, a[j]);
        }
    }
    __syncthreads();

    // ---- out-projection GEMM: M=192 (w_out rows), N=128 (t), K=192 (d) ----
    const int l = tid & 63;
    const int wave = tid >> 6;
    const int wm = wave >> 2;           // 0..1  (96 M-rows each)
    const int wn = wave & 3;            // 0..3  (32 t-cols each)

    f32x16 acc[3];
    #pragma unroll
    for (int mf = 0; mf < 3; ++mf)
        #pragma unroll
        for (int r = 0; r < 16; ++r) acc[mf][r] = 0.f;

    auto stageA = [&](int ks, int bf) {
        int idx = tid;
        int row = idx >> 2;
        int cb = (idx & 3) ^ ((row >> 1) & 3);
        gload16(wh + (size_t)(576 + row) * Cn + ks * 32 + cb * 8, Ah_ + bf * ASZ + idx * 8);
        gload16(wl + (size_t)(576 + row) * Cn + ks * 32 + cb * 8, Al_ + bf * ASZ + idx * 8);
        if (tid < 256) {
            idx = 512 + tid;
            row = idx >> 2;
            cb = (idx & 3) ^ ((row >> 1) & 3);
            gload16(wh + (size_t)(576 + row) * Cn + ks * 32 + cb * 8, Ah_ + bf * ASZ + idx * 8);
            gload16(wl + (size_t)(576 + row) * Cn + ks * 32 + cb * 8, Al_ + bf * ASZ + idx * 8);
        }
    };

    stageA(0, 0);
    __syncthreads();                     // A(0) drained
    for (int ks = 0; ks < 6; ++ks) {
        if (ks < 5) stageA(ks + 1, (ks + 1) & 1);   // issue early, other buffer
        {
            const int bf = ks & 1;
            #pragma unroll
            for (int kh = 0; kh < 2; ++kh) {
                const int cbb = kh * 2 + (l >> 5);
                bf16x8 ah[3], al[3];
                #pragma unroll
                for (int mf = 0; mf < 3; ++mf) {
                    int r = wm * 96 + mf * 32 + (l & 31);
                    int off = bf * ASZ + r * 32 + ((cbb ^ ((r >> 1) & 3)) << 3);
                    ah[mf] = *(const bf16x8*)&Ah_[off];
                    al[mf] = *(const bf16x8*)&Al_[off];
                }
                const int t = wn * 32 + (l & 31);
                const int o = t * 196 + ks * 32 + cbb * 8;
                union { uint2 q[2]; bf16x8 v; } bh, bl;
                bh.q[0] = *(const uint2*)&Yh_[o];
                bh.q[1] = *(const uint2*)&Yh_[o + 4];
                bl.q[0] = *(const uint2*)&Yl_[o];
                bl.q[1] = *(const uint2*)&Yl_[o + 4];
                #pragma unroll
                for (int mf = 0; mf < 3; ++mf) {
                    acc[mf] = __builtin_amdgcn_mfma_f32_32x32x16_bf16(ah[mf], bh.v, acc[mf], 0, 0, 0);
                    acc[mf] = __builtin_amdgcn_mfma_f32_32x32x16_bf16(ah[mf], bl.v, acc[mf], 0, 0, 0);
                    acc[mf] = __builtin_amdgcn_mfma_f32_32x32x16_bf16(al[mf], bh.v, acc[mf], 0, 0, 0);
                }
            }
        }
        __syncthreads();                 // A(ks+1) drained + readers done
    }

    #pragma unroll
    for (int mf = 0; mf < 3; ++mf) {
        const int col = t0 + wn * 32 + (l & 31);
        #pragma unroll
        for (int r = 0; r < 16; ++r) {
            int row = wm * 96 + mf * 32 + (r & 3) + 8 * (r >> 2) + 4 * (l >> 5);
            out[((size_t)b * Cn + row) * Tn + col] = acc[mf][r];
        }
    }
}

// ---------------------------------------------------------------------------
extern "C" void kernel_launch(void* const* d_in, const int* in_sizes, int n_in,
                              void* d_out, int out_size, void* d_ws, size_t ws_size,
                              hipStream_t stream) {
    const float* x        = (const float*)d_in[0];
    const float* w_key    = (const float*)d_in[1];
    const float* w_value  = (const float*)d_in[2];
    const float* w_recept = (const float*)d_in[3];
    const float* w_out    = (const float*)d_in[4];
    const float* decay    = (const float*)d_in[5];
    const float* boost    = (const float*)d_in[6];
    const float* alpha    = (const float*)d_in[7];
    const float* dw1      = (const float*)d_in[8];
    const float* dw3      = (const float*)d_in[9];
    const float* dw5      = (const float*)d_in[10];

    const size_t S = (size_t)Bn * Cn * Tn;   // 6291456 elements
    u16* R0 = (u16*)d_ws;                    // 2S u16 each region
    u16* R1 = R0 + 2 * S;
    u16* R2 = R1 + 2 * S;
    u16* whp = R2 + 2 * S;                   // stacked weights hi (4*36864)
    u16* wlp = whp + 4 * 36864;

    u16* xs_hi = R0;        u16* xs_lo = R0 + S;      // omni out / proj in
    float* kb  = (float*)R1;                          // proj out
    float* vb  = (float*)R2;
    float* srl = (float*)d_out;                       // scratch until wkv_out
    float4* states = (float4*)R0;                     // after xs dead (6.3 MB)
    float* out = (float*)d_out;

    // blocks 1536..1727 also perform the weight hi/lo split
    omni_kernel<<<dim3(1536 + 192), 256, 0, stream>>>(x, alpha, dw1, dw3, dw5,
                                                      w_key, w_value, w_recept, w_out,
                                                      xs_hi, xs_lo, whp, wlp);

    gemm_proj<<<dim3(32, 3, 8), 256, 0, stream>>>(whp, wlp, xs_hi, xs_lo, kb, vb, srl);

    wkv_stats<<<dim3(Bn * Cn), 256, 0, stream>>>(kb, vb, decay, states);

    wkv_out<<<dim3(32, 8), 512, 0, stream>>>(kb, vb, srl, states, decay, boost,
                                             whp, wlp, out);
}